// Round 5
// baseline (203.271 us; speedup 1.0000x reference)
//
#include <hip/hip_runtime.h>
#include <hip/hip_bf16.h>

typedef __bf16 bf16x8 __attribute__((ext_vector_type(8)));
typedef __bf16 bf16x4 __attribute__((ext_vector_type(4)));
typedef float f32x4 __attribute__((ext_vector_type(4)));

#define SEQ   2048
#define NB    2
#define NTOK  4096
#define HIDD  512
#define NHEAD 16
#define DHEAD 64
#define QKVN  3072
#define GUN   2048

// workspace layout (bytes)
#define OFF_WQKVT  0u
#define OFF_WOT    3145728u
#define OFF_WGUT   4194304u
#define OFF_WDT    6291456u
#define OFF_HB     7340032u
#define OFF_QKV    11534336u
#define OFF_ATTN   36700160u
#define OFF_H2     45088768u
#define OFF_G      53477376u
#define OFF_M      (OFF_QKV + 16777216u)

#define QSCALE 0.1803368801111731f          // 0.125 * log2(e): exp2-domain scores

typedef unsigned int __attribute__((address_space(1))) as1_uint;
typedef unsigned int __attribute__((address_space(3))) as3_uint;
__device__ __forceinline__ void gload16(const void* g, void* l) {
    __builtin_amdgcn_global_load_lds((const as1_uint*)g, (as3_uint*)l, 16, 0, 0);
}

// ---------------- all 7 weight transposes in one launch ----------------
__global__ __launch_bounds__(256) void transpose_all_k(
    const float* __restrict__ wq, const float* __restrict__ wk,
    const float* __restrict__ wv, const float* __restrict__ wo,
    const float* __restrict__ wg, const float* __restrict__ wu,
    const float* __restrict__ wd,
    __bf16* __restrict__ qkvT, __bf16* __restrict__ woT,
    __bf16* __restrict__ wguT, __bf16* __restrict__ wdT) {
    __shared__ float t[32][33];
    int which = blockIdx.y;
    const float* in; __bf16* out; int K, N, mode = 0, phase = 0;
    switch (which) {
        case 0: in = wq; out = qkvT;              K = 512;  N = 1024; break;
        case 1: in = wk; out = qkvT + 1024 * 512; K = 512;  N = 1024; break;
        case 2: in = wv; out = qkvT + 2048 * 512; K = 512;  N = 1024; break;
        case 3: in = wo; out = woT;               K = 1024; N = 512;  break;
        case 4: in = wg; out = wguT;              K = 512;  N = 1024; mode = 1; phase = 0; break;
        case 5: in = wu; out = wguT;              K = 512;  N = 1024; mode = 1; phase = 1; break;
        default: in = wd; out = wdT;              K = 1024; N = 512;  break;
    }
    int ntn = N >> 5;
    int n0 = (blockIdx.x & (ntn - 1)) * 32;
    int k0 = (blockIdx.x / ntn) * 32;
    int tx = threadIdx.x & 31, ty = threadIdx.x >> 5;
#pragma unroll
    for (int j = 0; j < 4; ++j)
        t[ty * 4 + j][tx] = in[(size_t)(k0 + ty * 4 + j) * N + n0 + tx];
    __syncthreads();
#pragma unroll
    for (int j = 0; j < 4; ++j) {
        int n = n0 + ty * 4 + j;
        int row = mode ? (((n >> 4) << 5) + phase * 16 + (n & 15)) : n;
        out[(size_t)row * K + k0 + tx] = (__bf16)t[tx][ty * 4 + j];
    }
}

// ---------------- RMSNorm ----------------
__global__ __launch_bounds__(256) void rmsnorm_k(const float* __restrict__ x,
                                                 const float* __restrict__ w,
                                                 __bf16* __restrict__ out) {
    int row = blockIdx.x;
    int t = threadIdx.x;
    const float* xr = x + (size_t)row * HIDD;
    float2 v = *(const float2*)&xr[t * 2];
    float ss = v.x * v.x + v.y * v.y;
#pragma unroll
    for (int off = 32; off >= 1; off >>= 1) ss += __shfl_xor(ss, off);
    __shared__ float red[4];
    if ((t & 63) == 0) red[t >> 6] = ss;
    __syncthreads();
    float tot = red[0] + red[1] + red[2] + red[3];
    float r = rsqrtf(tot * (1.0f / HIDD) + 1e-8f);
    out[(size_t)row * HIDD + t * 2]     = (__bf16)(v.x * r * w[t * 2]);
    out[(size_t)row * HIDD + t * 2 + 1] = (__bf16)(v.y * r * w[t * 2 + 1]);
}

// ---------------- GEMM: C[M][N] = A[M][K] * Bt[N][K]^T ----------------
template <int EPI, int TM, int TN>
__global__ __launch_bounds__(256) void gemm_bt(const __bf16* __restrict__ A,
                                               const __bf16* __restrict__ Bt,
                                               int M, int N, int K,
                                               __bf16* __restrict__ Cb,
                                               float* __restrict__ Cf,
                                               const float* __restrict__ resid,
                                               const float* __restrict__ scale,
                                               const float* __restrict__ cosv,
                                               const float* __restrict__ sinv) {
    __shared__ alignas(16) __bf16 As[TM][32];
    __shared__ alignas(16) __bf16 Bs[TN][32];
    constexpr int MI = TM / 32, NI = TN / 32;
    int m0 = blockIdx.y * TM, n0 = blockIdx.x * TN;
    int tid = threadIdx.x;
    int lane = tid & 63, w = tid >> 6;
    int wm = (w >> 1) * (TM / 2), wn = (w & 1) * (TN / 2);
    int lr = lane & 15, lkg = lane >> 4, lk = lkg * 8;
    f32x4 acc[MI][NI] = {};
    int nkt = K >> 5;
    for (int kt = 0; kt < nkt; ++kt) {
        __syncthreads();
#pragma unroll
        for (int i = 0; i < (TM * 4) / 256; ++i) {
            int c = i * 256 + tid;
            int row = c >> 2, k8 = (c & 3) << 3;
            gload16(&A[(size_t)(m0 + row) * K + kt * 32 + k8], &As[row][k8]);
        }
#pragma unroll
        for (int i = 0; i < (TN * 4) / 256; ++i) {
            int c = i * 256 + tid;
            int row = c >> 2, k8 = (c & 3) << 3;
            gload16(&Bt[(size_t)(n0 + row) * K + kt * 32 + k8], &Bs[row][k8]);
        }
        __syncthreads();
        bf16x8 af[MI], bfv[NI];
#pragma unroll
        for (int mi = 0; mi < MI; ++mi) af[mi] = *(const bf16x8*)&As[wm + mi * 16 + lr][lk];
#pragma unroll
        for (int ni = 0; ni < NI; ++ni) bfv[ni] = *(const bf16x8*)&Bs[wn + ni * 16 + lr][lk];
#pragma unroll
        for (int mi = 0; mi < MI; ++mi)
#pragma unroll
            for (int ni = 0; ni < NI; ++ni)
                acc[mi][ni] = __builtin_amdgcn_mfma_f32_16x16x32_bf16(
                    af[mi], bfv[ni], acc[mi][ni], 0, 0, 0);
    }
    if (EPI == 1) {
        bool do_rope = (n0 + wn) < 2048;
        float qf = (n0 + wn) < 1024 ? QSCALE : 1.0f;
#pragma unroll
        for (int mi = 0; mi < MI; ++mi)
#pragma unroll
            for (int r = 0; r < 4; ++r) {
                int row = m0 + wm + mi * 16 + lkg * 4 + r;
                int s = row & (SEQ - 1);
#pragma unroll
                for (int ni = 0; ni < 2; ++ni) {
                    float v1 = acc[mi][ni][r], v2 = acc[mi][ni + 2][r];
                    size_t i1 = (size_t)row * N + n0 + wn + ni * 16 + lr;
                    size_t i2 = i1 + 32;
                    if (do_rope) {
                        int d = ni * 16 + lr;
                        float c = cosv[s * 32 + d], sn = sinv[s * 32 + d];
                        Cb[i1] = (__bf16)((v1 * c - v2 * sn) * qf);
                        Cb[i2] = (__bf16)((v2 * c + v1 * sn) * qf);
                    } else {
                        Cb[i1] = (__bf16)v1;
                        Cb[i2] = (__bf16)v2;
                    }
                }
            }
    } else if (EPI == 3) {
#pragma unroll
        for (int mi = 0; mi < MI; ++mi)
#pragma unroll
            for (int r = 0; r < 4; ++r) {
                int row = m0 + wm + mi * 16 + lkg * 4 + r;
#pragma unroll
                for (int ni = 0; ni < 4; ni += 2) {
                    float g = acc[mi][ni][r], u = acc[mi][ni + 1][r];
                    float mv = (g / (1.0f + __expf(-g))) * u;
                    int j = (((n0 + wn + ni * 16) >> 5) << 4) + lr;
                    Cb[(size_t)row * 1024 + j] = (__bf16)mv;
                }
            }
    } else {
#pragma unroll
        for (int mi = 0; mi < MI; ++mi)
#pragma unroll
            for (int ni = 0; ni < NI; ++ni)
#pragma unroll
                for (int r = 0; r < 4; ++r) {
                    int row = m0 + wm + mi * 16 + lkg * 4 + r;
                    int col = n0 + wn + ni * 16 + lr;
                    size_t idx = (size_t)row * N + col;
                    float vv = acc[mi][ni][r];
                    if (EPI == 0) Cb[idx] = (__bf16)vv;
                    else          Cf[idx] = resid[idx] + vv * scale[col];
                }
    }
}

// ---------------- causal flash attention, paired q-tiles ----------------
// grid = (NB*NHEAD, 16). Block y owns q-tiles {y, 31-y}: shares K/V staging,
// computes exactly 33 tile-MFMAs -> perfect balance. 4 waves x (16+16) q-rows.
// Swapped-operand MFMAs (q = lane&15 throughout), P in registers,
// double-buffered K/V pipeline.
__global__ __launch_bounds__(256, 4) void attn_k(const __bf16* __restrict__ qkv,
                                                 __bf16* __restrict__ outp) {
    __shared__ alignas(16) __bf16 KtF[2][64 * 64];   // [key][d], source-swizzled
    __shared__ alignas(16) __bf16 VtF[2][64 * 64];   // [dv][pi-key], swizzled
    int bh = blockIdx.x;
    int b = bh >> 4, h = bh & 15;
    int qbA = blockIdx.y;            // small tile: needs kb 0..qbA
    int qbB = 31 - qbA;              // large tile: needs kb 0..qbB
    int tid = threadIdx.x, lane = tid & 63, w = tid >> 6;
    int lq = lane & 15, g = lane >> 4;
    int qr0A = qbA * 64 + w * 16, qr0B = qbB * 64 + w * 16;
    size_t tokb = (size_t)b * SEQ;

    // V staging constants (pi-key permutation matching the register-P B-frag)
    int vkey = lane;
    int vslot = ((vkey >> 5) << 2) + ((vkey >> 2) & 3);
    int vke   = (((vkey >> 4) & 1) << 2) + (vkey & 3);

    bf16x8 aqA[2], aqB[2];
#pragma unroll
    for (int ks = 0; ks < 2; ++ks) {
        aqA[ks] = *(const bf16x8*)&qkv[(tokb + qr0A + lq) * QKVN + h * 64 + ks * 32 + g * 8];
        aqB[ks] = *(const bf16x8*)&qkv[(tokb + qr0B + lq) * QKVN + h * 64 + ks * 32 + g * 8];
    }

    f32x4 oaA[4] = {}, oaB[4] = {};
    float mA = -1e30f, lA = 0.0f, mB = -1e30f, lB = 0.0f;
    uint4 vv0, vv1;
    int nkb = qbB + 1;
    int cur = 0;

    // ---- prologue: stage tile 0 into buf 0 ----
#pragma unroll
    for (int i = 0; i < 2; ++i) {
        int c = i * 256 + tid;
        int kr = c >> 3, s = c & 7;
        gload16(&qkv[(tokb + kr) * QKVN + 1024 + h * 64 + ((s ^ (kr & 7)) << 3)],
                &KtF[0][c * 8]);
    }
    vv0 = *(const uint4*)&qkv[(tokb + vkey) * QKVN + 2048 + h * 64 + (w * 2) * 8];
    vv1 = *(const uint4*)&qkv[(tokb + vkey) * QKVN + 2048 + h * 64 + (w * 2 + 1) * 8];
    {
        const __bf16* ve0 = (const __bf16*)&vv0;
        const __bf16* ve1 = (const __bf16*)&vv1;
#pragma unroll
        for (int j = 0; j < 8; ++j) {
            int dv0 = (w * 2) * 8 + j, dv1 = (w * 2 + 1) * 8 + j;
            VtF[0][dv0 * 64 + ((vslot ^ j) << 3) + vke] = ve0[j];
            VtF[0][dv1 * 64 + ((vslot ^ j) << 3) + vke] = ve1[j];
        }
    }
    __syncthreads();

    for (int kb = 0; kb < nkb; ++kb) {
        bool pf = (kb + 1) < nkb;
        if (pf) {
#pragma unroll
            for (int i = 0; i < 2; ++i) {
                int c = i * 256 + tid;
                int kr = c >> 3, s = c & 7;
                gload16(&qkv[(tokb + (kb + 1) * 64 + kr) * QKVN + 1024 + h * 64 + ((s ^ (kr & 7)) << 3)],
                        &KtF[cur ^ 1][c * 8]);
            }
            vv0 = *(const uint4*)&qkv[(tokb + (kb + 1) * 64 + vkey) * QKVN + 2048 + h * 64 + (w * 2) * 8];
            vv1 = *(const uint4*)&qkv[(tokb + (kb + 1) * 64 + vkey) * QKVN + 2048 + h * 64 + (w * 2 + 1) * 8];
        }
        bool actA = kb <= qbA;  // block-uniform

        // ================= tile B (always active) =================
        {
            f32x4 sc[4] = {};
            __builtin_amdgcn_s_setprio(1);
#pragma unroll
            for (int jt = 0; jt < 4; ++jt)
#pragma unroll
                for (int ks = 0; ks < 2; ++ks) {
                    bf16x8 bk = *(const bf16x8*)&KtF[cur][(jt * 16 + lq) * 64 + (((ks * 4 + g) ^ (lq & 7)) << 3)];
                    sc[jt] = __builtin_amdgcn_mfma_f32_16x16x32_bf16(bk, aqB[ks], sc[jt], 0, 0, 0);
                }
            __builtin_amdgcn_s_setprio(0);
            if (kb == qbB) {
                int qabs = qr0B + lq;
#pragma unroll
                for (int jt = 0; jt < 4; ++jt)
#pragma unroll
                    for (int r = 0; r < 4; ++r) {
                        int key = kb * 64 + jt * 16 + g * 4 + r;
                        if (key > qabs) sc[jt][r] = -1e9f;
                    }
            }
            float m0 = fmaxf(fmaxf(sc[0][0], sc[0][1]), fmaxf(sc[0][2], sc[0][3]));
            float m1 = fmaxf(fmaxf(sc[1][0], sc[1][1]), fmaxf(sc[1][2], sc[1][3]));
            float m2 = fmaxf(fmaxf(sc[2][0], sc[2][1]), fmaxf(sc[2][2], sc[2][3]));
            float m3 = fmaxf(fmaxf(sc[3][0], sc[3][1]), fmaxf(sc[3][2], sc[3][3]));
            float mx = fmaxf(fmaxf(m0, m1), fmaxf(m2, m3));
            mx = fmaxf(mx, __shfl_xor(mx, 16));
            mx = fmaxf(mx, __shfl_xor(mx, 32));
            if (__any(mx > mB + 8.0f)) {
                float mn = fmaxf(mB, mx);
                float al = exp2f(mB - mn);
                mB = mn;
#pragma unroll
                for (int dt = 0; dt < 4; ++dt) oaB[dt] *= al;
                lB *= al;
            }
#pragma unroll
            for (int jt = 0; jt < 4; ++jt)
#pragma unroll
                for (int r = 0; r < 4; ++r) {
                    float p = exp2f(sc[jt][r] - mB);
                    sc[jt][r] = p;
                    lB += p;
                }
            __builtin_amdgcn_s_setprio(1);
#pragma unroll
            for (int ks2 = 0; ks2 < 2; ++ks2) {
                bf16x8 pfv;
#pragma unroll
                for (int e = 0; e < 4; ++e) {
                    pfv[e]     = (__bf16)sc[2 * ks2][e];
                    pfv[e + 4] = (__bf16)sc[2 * ks2 + 1][e];
                }
#pragma unroll
                for (int dt = 0; dt < 4; ++dt) {
                    bf16x8 av = *(const bf16x8*)&VtF[cur][(dt * 16 + lq) * 64 + (((ks2 * 4 + g) ^ (lq & 7)) << 3)];
                    oaB[dt] = __builtin_amdgcn_mfma_f32_16x16x32_bf16(av, pfv, oaB[dt], 0, 0, 0);
                }
            }
            __builtin_amdgcn_s_setprio(0);
        }

        // ================= tile A (active while kb <= qbA) =================
        if (actA) {
            f32x4 sc[4] = {};
            __builtin_amdgcn_s_setprio(1);
#pragma unroll
            for (int jt = 0; jt < 4; ++jt)
#pragma unroll
                for (int ks = 0; ks < 2; ++ks) {
                    bf16x8 bk = *(const bf16x8*)&KtF[cur][(jt * 16 + lq) * 64 + (((ks * 4 + g) ^ (lq & 7)) << 3)];
                    sc[jt] = __builtin_amdgcn_mfma_f32_16x16x32_bf16(bk, aqA[ks], sc[jt], 0, 0, 0);
                }
            __builtin_amdgcn_s_setprio(0);
            if (kb == qbA) {
                int qabs = qr0A + lq;
#pragma unroll
                for (int jt = 0; jt < 4; ++jt)
#pragma unroll
                    for (int r = 0; r < 4; ++r) {
                        int key = kb * 64 + jt * 16 + g * 4 + r;
                        if (key > qabs) sc[jt][r] = -1e9f;
                    }
            }
            float m0 = fmaxf(fmaxf(sc[0][0], sc[0][1]), fmaxf(sc[0][2], sc[0][3]));
            float m1 = fmaxf(fmaxf(sc[1][0], sc[1][1]), fmaxf(sc[1][2], sc[1][3]));
            float m2 = fmaxf(fmaxf(sc[2][0], sc[2][1]), fmaxf(sc[2][2], sc[2][3]));
            float m3 = fmaxf(fmaxf(sc[3][0], sc[3][1]), fmaxf(sc[3][2], sc[3][3]));
            float mx = fmaxf(fmaxf(m0, m1), fmaxf(m2, m3));
            mx = fmaxf(mx, __shfl_xor(mx, 16));
            mx = fmaxf(mx, __shfl_xor(mx, 32));
            if (__any(mx > mA + 8.0f)) {
                float mn = fmaxf(mA, mx);
                float al = exp2f(mA - mn);
                mA = mn;
#pragma unroll
                for (int dt = 0; dt < 4; ++dt) oaA[dt] *= al;
                lA *= al;
            }
#pragma unroll
            for (int jt = 0; jt < 4; ++jt)
#pragma unroll
                for (int r = 0; r < 4; ++r) {
                    float p = exp2f(sc[jt][r] - mA);
                    sc[jt][r] = p;
                    lA += p;
                }
            __builtin_amdgcn_s_setprio(1);
#pragma unroll
            for (int ks2 = 0; ks2 < 2; ++ks2) {
                bf16x8 pfv;
#pragma unroll
                for (int e = 0; e < 4; ++e) {
                    pfv[e]     = (__bf16)sc[2 * ks2][e];
                    pfv[e + 4] = (__bf16)sc[2 * ks2 + 1][e];
                }
#pragma unroll
                for (int dt = 0; dt < 4; ++dt) {
                    bf16x8 av = *(const bf16x8*)&VtF[cur][(dt * 16 + lq) * 64 + (((ks2 * 4 + g) ^ (lq & 7)) << 3)];
                    oaA[dt] = __builtin_amdgcn_mfma_f32_16x16x32_bf16(av, pfv, oaA[dt], 0, 0, 0);
                }
            }
            __builtin_amdgcn_s_setprio(0);
        }

        if (pf) {
            const __bf16* ve0 = (const __bf16*)&vv0;
            const __bf16* ve1 = (const __bf16*)&vv1;
#pragma unroll
            for (int j = 0; j < 8; ++j) {
                int dv0 = (w * 2) * 8 + j, dv1 = (w * 2 + 1) * 8 + j;
                VtF[cur ^ 1][dv0 * 64 + ((vslot ^ j) << 3) + vke] = ve0[j];
                VtF[cur ^ 1][dv1 * 64 + ((vslot ^ j) << 3) + vke] = ve1[j];
            }
        }
        __syncthreads();
        cur ^= 1;
    }

    // epilogues
    lA += __shfl_xor(lA, 16);
    lA += __shfl_xor(lA, 32);
    lB += __shfl_xor(lB, 16);
    lB += __shfl_xor(lB, 32);
    float invA = 1.0f / lA, invB = 1.0f / lB;
#pragma unroll
    for (int dt = 0; dt < 4; ++dt) {
        bf16x4 ovA, ovB;
#pragma unroll
        for (int r = 0; r < 4; ++r) {
            ovA[r] = (__bf16)(oaA[dt][r] * invA);
            ovB[r] = (__bf16)(oaB[dt][r] * invB);
        }
        *(bf16x4*)&outp[(tokb + qr0A + lq) * 1024 + h * 64 + dt * 16 + g * 4] = ovA;
        *(bf16x4*)&outp[(tokb + qr0B + lq) * 1024 + h * 64 + dt * 16 + g * 4] = ovB;
    }
}

// ---------------- launch ----------------
extern "C" void kernel_launch(void* const* d_in, const int* in_sizes, int n_in,
                              void* d_out, int out_size, void* d_ws, size_t ws_size,
                              hipStream_t stream) {
    const float* x       = (const float*)d_in[0];
    const float* cosv    = (const float*)d_in[1];
    const float* sinv    = (const float*)d_in[2];
    const float* wq      = (const float*)d_in[4];
    const float* wk      = (const float*)d_in[5];
    const float* wv      = (const float*)d_in[6];
    const float* wo      = (const float*)d_in[7];
    const float* wgate   = (const float*)d_in[8];
    const float* wup     = (const float*)d_in[9];
    const float* wdown   = (const float*)d_in[10];
    const float* norm1   = (const float*)d_in[11];
    const float* norm2   = (const float*)d_in[12];
    const float* ls_attn = (const float*)d_in[13];
    const float* ls_mlp  = (const float*)d_in[14];

    char* ws = (char*)d_ws;
    __bf16* wqkvT = (__bf16*)(ws + OFF_WQKVT);
    __bf16* woT   = (__bf16*)(ws + OFF_WOT);
    __bf16* wguT  = (__bf16*)(ws + OFF_WGUT);
    __bf16* wdT   = (__bf16*)(ws + OFF_WDT);
    __bf16* hb    = (__bf16*)(ws + OFF_HB);
    __bf16* qkvb  = (__bf16*)(ws + OFF_QKV);
    __bf16* attnb = (__bf16*)(ws + OFF_ATTN);
    float*  h2    = (float*)(ws + OFF_H2);
    __bf16* gb    = (__bf16*)(ws + OFF_G);
    __bf16* mb    = (__bf16*)(ws + OFF_M);
    float*  outf  = (float*)d_out;

    transpose_all_k<<<dim3(512, 7), 256, 0, stream>>>(
        wq, wk, wv, wo, wgate, wup, wdown, wqkvT, woT, wguT, wdT);

    rmsnorm_k<<<NTOK, 256, 0, stream>>>(x, norm1, hb);
    gemm_bt<1, 128, 128><<<dim3(QKVN / 128, NTOK / 128), 256, 0, stream>>>(
        hb, wqkvT, NTOK, QKVN, 512, qkvb, nullptr, nullptr, nullptr, cosv, sinv);
    attn_k<<<dim3(NB * NHEAD, 16), 256, 0, stream>>>(qkvb, attnb);
    gemm_bt<2, 64, 64><<<dim3(HIDD / 64, NTOK / 64), 256, 0, stream>>>(
        attnb, woT, NTOK, HIDD, 1024, nullptr, h2, x, ls_attn, nullptr, nullptr);
    rmsnorm_k<<<NTOK, 256, 0, stream>>>(h2, norm2, gb);
    gemm_bt<3, 128, 128><<<dim3(GUN / 128, NTOK / 128), 256, 0, stream>>>(
        gb, wguT, NTOK, GUN, 512, mb, nullptr, nullptr, nullptr, nullptr, nullptr);
    gemm_bt<2, 64, 64><<<dim3(HIDD / 64, NTOK / 64), 256, 0, stream>>>(
        mb, wdT, NTOK, HIDD, 1024, nullptr, outf, h2, ls_mlp, nullptr, nullptr);
}

// Round 6
// 148.149 us; speedup vs baseline: 1.3721x; 1.3721x over previous
//
#include <hip/hip_runtime.h>
#include <hip/hip_bf16.h>

typedef __bf16 bf16x8 __attribute__((ext_vector_type(8)));
typedef __bf16 bf16x4 __attribute__((ext_vector_type(4)));
typedef float f32x4 __attribute__((ext_vector_type(4)));

#define SEQ   2048
#define NB    2
#define NTOK  4096
#define HIDD  512
#define NHEAD 16
#define DHEAD 64
#define QKVN  3072
#define GUN   2048

// workspace layout (bytes)
#define OFF_WQKVT  0u
#define OFF_WOT    3145728u
#define OFF_WGUT   4194304u
#define OFF_WDT    6291456u
#define OFF_HB     7340032u
#define OFF_QKV    11534336u
#define OFF_ATTN   36700160u
#define OFF_H2     45088768u
#define OFF_G      53477376u
#define OFF_M      (OFF_QKV + 16777216u)

#define QSCALE 0.1803368801111731f          // 0.125 * log2(e): exp2-domain scores

typedef unsigned int __attribute__((address_space(1))) as1_uint;
typedef unsigned int __attribute__((address_space(3))) as3_uint;
__device__ __forceinline__ void gload16(const void* g, void* l) {
    __builtin_amdgcn_global_load_lds((const as1_uint*)g, (as3_uint*)l, 16, 0, 0);
}

// ---------------- all 7 weight transposes in one launch ----------------
__global__ __launch_bounds__(256) void transpose_all_k(
    const float* __restrict__ wq, const float* __restrict__ wk,
    const float* __restrict__ wv, const float* __restrict__ wo,
    const float* __restrict__ wg, const float* __restrict__ wu,
    const float* __restrict__ wd,
    __bf16* __restrict__ qkvT, __bf16* __restrict__ woT,
    __bf16* __restrict__ wguT, __bf16* __restrict__ wdT) {
    __shared__ float t[32][33];
    int which = blockIdx.y;
    const float* in; __bf16* out; int K, N, mode = 0, phase = 0;
    switch (which) {
        case 0: in = wq; out = qkvT;              K = 512;  N = 1024; break;
        case 1: in = wk; out = qkvT + 1024 * 512; K = 512;  N = 1024; break;
        case 2: in = wv; out = qkvT + 2048 * 512; K = 512;  N = 1024; break;
        case 3: in = wo; out = woT;               K = 1024; N = 512;  break;
        case 4: in = wg; out = wguT;              K = 512;  N = 1024; mode = 1; phase = 0; break;
        case 5: in = wu; out = wguT;              K = 512;  N = 1024; mode = 1; phase = 1; break;
        default: in = wd; out = wdT;              K = 1024; N = 512;  break;
    }
    int ntn = N >> 5;
    int n0 = (blockIdx.x & (ntn - 1)) * 32;
    int k0 = (blockIdx.x / ntn) * 32;
    int tx = threadIdx.x & 31, ty = threadIdx.x >> 5;
#pragma unroll
    for (int j = 0; j < 4; ++j)
        t[ty * 4 + j][tx] = in[(size_t)(k0 + ty * 4 + j) * N + n0 + tx];
    __syncthreads();
#pragma unroll
    for (int j = 0; j < 4; ++j) {
        int n = n0 + ty * 4 + j;
        int row = mode ? (((n >> 4) << 5) + phase * 16 + (n & 15)) : n;
        out[(size_t)row * K + k0 + tx] = (__bf16)t[tx][ty * 4 + j];
    }
}

// ---------------- RMSNorm ----------------
__global__ __launch_bounds__(256) void rmsnorm_k(const float* __restrict__ x,
                                                 const float* __restrict__ w,
                                                 __bf16* __restrict__ out) {
    int row = blockIdx.x;
    int t = threadIdx.x;
    const float* xr = x + (size_t)row * HIDD;
    float2 v = *(const float2*)&xr[t * 2];
    float ss = v.x * v.x + v.y * v.y;
#pragma unroll
    for (int off = 32; off >= 1; off >>= 1) ss += __shfl_xor(ss, off);
    __shared__ float red[4];
    if ((t & 63) == 0) red[t >> 6] = ss;
    __syncthreads();
    float tot = red[0] + red[1] + red[2] + red[3];
    float r = rsqrtf(tot * (1.0f / HIDD) + 1e-8f);
    out[(size_t)row * HIDD + t * 2]     = (__bf16)(v.x * r * w[t * 2]);
    out[(size_t)row * HIDD + t * 2 + 1] = (__bf16)(v.y * r * w[t * 2 + 1]);
}

// ---------------- GEMM: C[M][N] = A[M][K] * Bt[N][K]^T ----------------
template <int EPI, int TM, int TN>
__global__ __launch_bounds__(256) void gemm_bt(const __bf16* __restrict__ A,
                                               const __bf16* __restrict__ Bt,
                                               int M, int N, int K,
                                               __bf16* __restrict__ Cb,
                                               float* __restrict__ Cf,
                                               const float* __restrict__ resid,
                                               const float* __restrict__ scale,
                                               const float* __restrict__ cosv,
                                               const float* __restrict__ sinv) {
    __shared__ alignas(16) __bf16 As[TM][32];
    __shared__ alignas(16) __bf16 Bs[TN][32];
    constexpr int MI = TM / 32, NI = TN / 32;
    int m0 = blockIdx.y * TM, n0 = blockIdx.x * TN;
    int tid = threadIdx.x;
    int lane = tid & 63, w = tid >> 6;
    int wm = (w >> 1) * (TM / 2), wn = (w & 1) * (TN / 2);
    int lr = lane & 15, lkg = lane >> 4, lk = lkg * 8;
    f32x4 acc[MI][NI] = {};
    int nkt = K >> 5;
    for (int kt = 0; kt < nkt; ++kt) {
        __syncthreads();
#pragma unroll
        for (int i = 0; i < (TM * 4) / 256; ++i) {
            int c = i * 256 + tid;
            int row = c >> 2, k8 = (c & 3) << 3;
            gload16(&A[(size_t)(m0 + row) * K + kt * 32 + k8], &As[row][k8]);
        }
#pragma unroll
        for (int i = 0; i < (TN * 4) / 256; ++i) {
            int c = i * 256 + tid;
            int row = c >> 2, k8 = (c & 3) << 3;
            gload16(&Bt[(size_t)(n0 + row) * K + kt * 32 + k8], &Bs[row][k8]);
        }
        __syncthreads();
        bf16x8 af[MI], bfv[NI];
#pragma unroll
        for (int mi = 0; mi < MI; ++mi) af[mi] = *(const bf16x8*)&As[wm + mi * 16 + lr][lk];
#pragma unroll
        for (int ni = 0; ni < NI; ++ni) bfv[ni] = *(const bf16x8*)&Bs[wn + ni * 16 + lr][lk];
#pragma unroll
        for (int mi = 0; mi < MI; ++mi)
#pragma unroll
            for (int ni = 0; ni < NI; ++ni)
                acc[mi][ni] = __builtin_amdgcn_mfma_f32_16x16x32_bf16(
                    af[mi], bfv[ni], acc[mi][ni], 0, 0, 0);
    }
    if (EPI == 1) {
        bool do_rope = (n0 + wn) < 2048;
        float qf = (n0 + wn) < 1024 ? QSCALE : 1.0f;
#pragma unroll
        for (int mi = 0; mi < MI; ++mi)
#pragma unroll
            for (int r = 0; r < 4; ++r) {
                int row = m0 + wm + mi * 16 + lkg * 4 + r;
                int s = row & (SEQ - 1);
#pragma unroll
                for (int ni = 0; ni < 2; ++ni) {
                    float v1 = acc[mi][ni][r], v2 = acc[mi][ni + 2][r];
                    size_t i1 = (size_t)row * N + n0 + wn + ni * 16 + lr;
                    size_t i2 = i1 + 32;
                    if (do_rope) {
                        int d = ni * 16 + lr;
                        float c = cosv[s * 32 + d], sn = sinv[s * 32 + d];
                        Cb[i1] = (__bf16)((v1 * c - v2 * sn) * qf);
                        Cb[i2] = (__bf16)((v2 * c + v1 * sn) * qf);
                    } else {
                        Cb[i1] = (__bf16)v1;
                        Cb[i2] = (__bf16)v2;
                    }
                }
            }
    } else if (EPI == 3) {
#pragma unroll
        for (int mi = 0; mi < MI; ++mi)
#pragma unroll
            for (int r = 0; r < 4; ++r) {
                int row = m0 + wm + mi * 16 + lkg * 4 + r;
#pragma unroll
                for (int ni = 0; ni < 4; ni += 2) {
                    float g = acc[mi][ni][r], u = acc[mi][ni + 1][r];
                    float mv = (g / (1.0f + __expf(-g))) * u;
                    int j = (((n0 + wn + ni * 16) >> 5) << 4) + lr;
                    Cb[(size_t)row * 1024 + j] = (__bf16)mv;
                }
            }
    } else {
#pragma unroll
        for (int mi = 0; mi < MI; ++mi)
#pragma unroll
            for (int ni = 0; ni < NI; ++ni)
#pragma unroll
                for (int r = 0; r < 4; ++r) {
                    int row = m0 + wm + mi * 16 + lkg * 4 + r;
                    int col = n0 + wn + ni * 16 + lr;
                    size_t idx = (size_t)row * N + col;
                    float vv = acc[mi][ni][r];
                    if (EPI == 0) Cb[idx] = (__bf16)vv;
                    else          Cf[idx] = resid[idx] + vv * scale[col];
                }
    }
}

// ---------------- causal flash attention, paired q-tiles ----------------
// grid = (NB*NHEAD, 16). Block y owns q-tiles {y, 31-y}; K/V staging shared;
// exactly 33 tile-computes/block. Two-phase K loop (both tiles, then B only).
// Swapped-operand MFMAs (q = lane&15), P in registers, double-buffered K/V.
// __launch_bounds__(256,2): 256-VGPR cap — the (256,4)=128 cap caused the
// round-5 spill (WRITE_SIZE 26.5MB vs 8.4MB legit). 512 blocks = 2/CU anyway.
__global__ __launch_bounds__(256, 2) void attn_k(const __bf16* __restrict__ qkv,
                                                 __bf16* __restrict__ outp) {
    __shared__ alignas(16) __bf16 KtF[2][64 * 64];   // [key][d], source-swizzled
    __shared__ alignas(16) __bf16 VtF[2][64 * 64];   // [dv][pi-key], swizzled
    int bh = blockIdx.x;
    int b = bh >> 4, h = bh & 15;
    int qbA = blockIdx.y;            // small tile: kb 0..qbA
    int qbB = 31 - qbA;              // large tile: kb 0..qbB
    int tid = threadIdx.x, lane = tid & 63, w = tid >> 6;
    int lq = lane & 15, g = lane >> 4;
    int qr0A = qbA * 64 + w * 16, qr0B = qbB * 64 + w * 16;
    size_t tokb = (size_t)b * SEQ;

    // V staging constants (pi-key permutation matching register-P B-frag)
    int vkey = lane;
    int vslot = ((vkey >> 5) << 2) + ((vkey >> 2) & 3);
    int vke   = (((vkey >> 4) & 1) << 2) + (vkey & 3);

    bf16x8 aqA[2], aqB[2];
#pragma unroll
    for (int ks = 0; ks < 2; ++ks) {
        aqA[ks] = *(const bf16x8*)&qkv[(tokb + qr0A + lq) * QKVN + h * 64 + ks * 32 + g * 8];
        aqB[ks] = *(const bf16x8*)&qkv[(tokb + qr0B + lq) * QKVN + h * 64 + ks * 32 + g * 8];
    }

    f32x4 oaA[4] = {}, oaB[4] = {};
    float mA = -1e30f, lA = 0.0f, mB = -1e30f, lB = 0.0f;
    uint4 vv0, vv1;
    int nkb = qbB + 1;
    int cur = 0;

    // ---- prologue: stage tile 0 into buf 0 ----
#pragma unroll
    for (int i = 0; i < 2; ++i) {
        int c = i * 256 + tid;
        int kr = c >> 3, s = c & 7;
        gload16(&qkv[(tokb + kr) * QKVN + 1024 + h * 64 + ((s ^ (kr & 7)) << 3)],
                &KtF[0][c * 8]);
    }
    vv0 = *(const uint4*)&qkv[(tokb + vkey) * QKVN + 2048 + h * 64 + (w * 2) * 8];
    vv1 = *(const uint4*)&qkv[(tokb + vkey) * QKVN + 2048 + h * 64 + (w * 2 + 1) * 8];
    {
        const __bf16* ve0 = (const __bf16*)&vv0;
        const __bf16* ve1 = (const __bf16*)&vv1;
#pragma unroll
        for (int j = 0; j < 8; ++j) {
            int dv0 = (w * 2) * 8 + j, dv1 = (w * 2 + 1) * 8 + j;
            VtF[0][dv0 * 64 + ((vslot ^ j) << 3) + vke] = ve0[j];
            VtF[0][dv1 * 64 + ((vslot ^ j) << 3) + vke] = ve1[j];
        }
    }
    __syncthreads();

#define STAGE_NEXT(kbn)                                                                          \
    {                                                                                            \
        _Pragma("unroll")                                                                        \
        for (int i = 0; i < 2; ++i) {                                                            \
            int c = i * 256 + tid;                                                               \
            int kr = c >> 3, s = c & 7;                                                          \
            gload16(&qkv[(tokb + (kbn) * 64 + kr) * QKVN + 1024 + h * 64 + ((s ^ (kr & 7)) << 3)], \
                    &KtF[cur ^ 1][c * 8]);                                                       \
        }                                                                                        \
        vv0 = *(const uint4*)&qkv[(tokb + (kbn) * 64 + vkey) * QKVN + 2048 + h * 64 + (w * 2) * 8];     \
        vv1 = *(const uint4*)&qkv[(tokb + (kbn) * 64 + vkey) * QKVN + 2048 + h * 64 + (w * 2 + 1) * 8]; \
    }

#define WRITE_V()                                                                 \
    {                                                                             \
        const __bf16* ve0 = (const __bf16*)&vv0;                                  \
        const __bf16* ve1 = (const __bf16*)&vv1;                                  \
        _Pragma("unroll")                                                         \
        for (int j = 0; j < 8; ++j) {                                             \
            int dv0 = (w * 2) * 8 + j, dv1 = (w * 2 + 1) * 8 + j;                 \
            VtF[cur ^ 1][dv0 * 64 + ((vslot ^ j) << 3) + vke] = ve0[j];           \
            VtF[cur ^ 1][dv1 * 64 + ((vslot ^ j) << 3) + vke] = ve1[j];           \
        }                                                                         \
    }

// one q-tile update against K/V tile `cur`; mask applied iff kb==qb_tile
#define TILE_STEP(aq, oa, m_run, l_run, qb_t, qr0_t, kb_t)                                       \
    {                                                                                            \
        f32x4 sc[4] = {};                                                                        \
        __builtin_amdgcn_s_setprio(1);                                                           \
        _Pragma("unroll")                                                                        \
        for (int jt = 0; jt < 4; ++jt)                                                           \
            _Pragma("unroll")                                                                    \
            for (int ks = 0; ks < 2; ++ks) {                                                     \
                bf16x8 bk = *(const bf16x8*)&KtF[cur][(jt * 16 + lq) * 64 + (((ks * 4 + g) ^ (lq & 7)) << 3)]; \
                sc[jt] = __builtin_amdgcn_mfma_f32_16x16x32_bf16(bk, aq[ks], sc[jt], 0, 0, 0);   \
            }                                                                                    \
        __builtin_amdgcn_s_setprio(0);                                                           \
        if ((kb_t) == (qb_t)) {                                                                  \
            int qabs = (qr0_t) + lq;                                                             \
            _Pragma("unroll")                                                                    \
            for (int jt = 0; jt < 4; ++jt)                                                       \
                _Pragma("unroll")                                                                \
                for (int r = 0; r < 4; ++r) {                                                    \
                    int key = (kb_t) * 64 + jt * 16 + g * 4 + r;                                 \
                    if (key > qabs) sc[jt][r] = -1e9f;                                           \
                }                                                                                \
        }                                                                                        \
        float m0 = fmaxf(fmaxf(sc[0][0], sc[0][1]), fmaxf(sc[0][2], sc[0][3]));                  \
        float m1 = fmaxf(fmaxf(sc[1][0], sc[1][1]), fmaxf(sc[1][2], sc[1][3]));                  \
        float m2 = fmaxf(fmaxf(sc[2][0], sc[2][1]), fmaxf(sc[2][2], sc[2][3]));                  \
        float m3 = fmaxf(fmaxf(sc[3][0], sc[3][1]), fmaxf(sc[3][2], sc[3][3]));                  \
        float mx = fmaxf(fmaxf(m0, m1), fmaxf(m2, m3));                                          \
        mx = fmaxf(mx, __shfl_xor(mx, 16));                                                      \
        mx = fmaxf(mx, __shfl_xor(mx, 32));                                                      \
        if (__any(mx > m_run + 8.0f)) {                                                          \
            float mn = fmaxf(m_run, mx);                                                         \
            float al = exp2f(m_run - mn);                                                        \
            m_run = mn;                                                                          \
            _Pragma("unroll")                                                                    \
            for (int dt = 0; dt < 4; ++dt) oa[dt] *= al;                                         \
            l_run *= al;                                                                         \
        }                                                                                        \
        _Pragma("unroll")                                                                        \
        for (int jt = 0; jt < 4; ++jt)                                                           \
            _Pragma("unroll")                                                                    \
            for (int r = 0; r < 4; ++r) {                                                        \
                float p = exp2f(sc[jt][r] - m_run);                                              \
                sc[jt][r] = p;                                                                   \
                l_run += p;                                                                      \
            }                                                                                    \
        __builtin_amdgcn_s_setprio(1);                                                           \
        _Pragma("unroll")                                                                        \
        for (int ks2 = 0; ks2 < 2; ++ks2) {                                                      \
            bf16x8 pfv;                                                                          \
            _Pragma("unroll")                                                                    \
            for (int e = 0; e < 4; ++e) {                                                        \
                pfv[e]     = (__bf16)sc[2 * ks2][e];                                             \
                pfv[e + 4] = (__bf16)sc[2 * ks2 + 1][e];                                         \
            }                                                                                    \
            _Pragma("unroll")                                                                    \
            for (int dt = 0; dt < 4; ++dt) {                                                     \
                bf16x8 av = *(const bf16x8*)&VtF[cur][(dt * 16 + lq) * 64 + (((ks2 * 4 + g) ^ (lq & 7)) << 3)]; \
                oa[dt] = __builtin_amdgcn_mfma_f32_16x16x32_bf16(av, pfv, oa[dt], 0, 0, 0);      \
            }                                                                                    \
        }                                                                                        \
        __builtin_amdgcn_s_setprio(0);                                                           \
    }

    // phase 1: kb = 0..qbA — both tiles consume the staged K/V
    for (int kb = 0; kb <= qbA; ++kb) {
        STAGE_NEXT(kb + 1);            // kb+1 <= qbA+1 <= qbB always valid here
        TILE_STEP(aqB, oaB, mB, lB, qbB, qr0B, kb);
        TILE_STEP(aqA, oaA, mA, lA, qbA, qr0A, kb);
        WRITE_V();
        __syncthreads();
        cur ^= 1;
    }
    // phase 2: kb = qbA+1..qbB — tile B only
    for (int kb = qbA + 1; kb < nkb; ++kb) {
        bool pf = (kb + 1) < nkb;
        if (pf) STAGE_NEXT(kb + 1);
        TILE_STEP(aqB, oaB, mB, lB, qbB, qr0B, kb);
        if (pf) WRITE_V();
        __syncthreads();
        cur ^= 1;
    }

    // epilogues
    lA += __shfl_xor(lA, 16);
    lA += __shfl_xor(lA, 32);
    lB += __shfl_xor(lB, 16);
    lB += __shfl_xor(lB, 32);
    float invA = 1.0f / lA, invB = 1.0f / lB;
#pragma unroll
    for (int dt = 0; dt < 4; ++dt) {
        bf16x4 ovA, ovB;
#pragma unroll
        for (int r = 0; r < 4; ++r) {
            ovA[r] = (__bf16)(oaA[dt][r] * invA);
            ovB[r] = (__bf16)(oaB[dt][r] * invB);
        }
        *(bf16x4*)&outp[(tokb + qr0A + lq) * 1024 + h * 64 + dt * 16 + g * 4] = ovA;
        *(bf16x4*)&outp[(tokb + qr0B + lq) * 1024 + h * 64 + dt * 16 + g * 4] = ovB;
    }
#undef STAGE_NEXT
#undef WRITE_V
#undef TILE_STEP
}

// ---------------- launch ----------------
extern "C" void kernel_launch(void* const* d_in, const int* in_sizes, int n_in,
                              void* d_out, int out_size, void* d_ws, size_t ws_size,
                              hipStream_t stream) {
    const float* x       = (const float*)d_in[0];
    const float* cosv    = (const float*)d_in[1];
    const float* sinv    = (const float*)d_in[2];
    const float* wq      = (const float*)d_in[4];
    const float* wk      = (const float*)d_in[5];
    const float* wv      = (const float*)d_in[6];
    const float* wo      = (const float*)d_in[7];
    const float* wgate   = (const float*)d_in[8];
    const float* wup     = (const float*)d_in[9];
    const float* wdown   = (const float*)d_in[10];
    const float* norm1   = (const float*)d_in[11];
    const float* norm2   = (const float*)d_in[12];
    const float* ls_attn = (const float*)d_in[13];
    const float* ls_mlp  = (const float*)d_in[14];

    char* ws = (char*)d_ws;
    __bf16* wqkvT = (__bf16*)(ws + OFF_WQKVT);
    __bf16* woT   = (__bf16*)(ws + OFF_WOT);
    __bf16* wguT  = (__bf16*)(ws + OFF_WGUT);
    __bf16* wdT   = (__bf16*)(ws + OFF_WDT);
    __bf16* hb    = (__bf16*)(ws + OFF_HB);
    __bf16* qkvb  = (__bf16*)(ws + OFF_QKV);
    __bf16* attnb = (__bf16*)(ws + OFF_ATTN);
    float*  h2    = (float*)(ws + OFF_H2);
    __bf16* gb    = (__bf16*)(ws + OFF_G);
    __bf16* mb    = (__bf16*)(ws + OFF_M);
    float*  outf  = (float*)d_out;

    transpose_all_k<<<dim3(512, 7), 256, 0, stream>>>(
        wq, wk, wv, wo, wgate, wup, wdown, wqkvT, woT, wguT, wdT);

    rmsnorm_k<<<NTOK, 256, 0, stream>>>(x, norm1, hb);
    gemm_bt<1, 128, 128><<<dim3(QKVN / 128, NTOK / 128), 256, 0, stream>>>(
        hb, wqkvT, NTOK, QKVN, 512, qkvb, nullptr, nullptr, nullptr, cosv, sinv);
    attn_k<<<dim3(NB * NHEAD, 16), 256, 0, stream>>>(qkvb, attnb);
    gemm_bt<2, 64, 64><<<dim3(HIDD / 64, NTOK / 64), 256, 0, stream>>>(
        attnb, woT, NTOK, HIDD, 1024, nullptr, h2, x, ls_attn, nullptr, nullptr);
    rmsnorm_k<<<NTOK, 256, 0, stream>>>(h2, norm2, gb);
    gemm_bt<3, 128, 128><<<dim3(GUN / 128, NTOK / 128), 256, 0, stream>>>(
        gb, wguT, NTOK, GUN, 512, mb, nullptr, nullptr, nullptr, nullptr, nullptr);
    gemm_bt<2, 64, 64><<<dim3(HIDD / 64, NTOK / 64), 256, 0, stream>>>(
        mb, wdT, NTOK, HIDD, 1024, nullptr, outf, h2, ls_mlp, nullptr, nullptr);
}